// Round 2
// baseline (216179.858 us; speedup 1.0000x reference)
//
#include <hip/hip_runtime.h>

#define VOCAB 60
#define EMB   100
#define HID   100
#define SEQN  262144
#define NPROJ 300   // 3*HID

__device__ __forceinline__ float fast_sig(float x) {
    return __builtin_amdgcn_rcpf(1.0f + __builtin_amdgcn_exp2f(-1.442695041f * x));
}
__device__ __forceinline__ float fast_tanh(float x) {
    return 2.0f * __builtin_amdgcn_rcpf(1.0f + __builtin_amdgcn_exp2f(-2.885390082f * x)) - 1.0f;
}

// proj[v][j] = emb[v]·w_ih[j] + b_ih[j] + (j<200 ? b_hh[j] : 0)
// w_t[k][j]  = w_hh[j][k]  (transpose -> coalesced weight loads in main kernel)
__global__ void precompute_kernel(const float* __restrict__ emb,
                                  const float* __restrict__ w_ih,
                                  const float* __restrict__ b_ih,
                                  const float* __restrict__ b_hh,
                                  const float* __restrict__ w_hh,
                                  float* __restrict__ proj,
                                  float* __restrict__ w_t)
{
    int idx = blockIdx.x * blockDim.x + threadIdx.x;
    if (idx < VOCAB * NPROJ) {
        int v = idx / NPROJ, j = idx - v * NPROJ;
        float acc = b_ih[j] + (j < 2 * HID ? b_hh[j] : 0.0f);
        const float* er = emb  + v * EMB;
        const float* wr = w_ih + j * EMB;
        #pragma unroll 4
        for (int k = 0; k < EMB; ++k) acc = fmaf(er[k], wr[k], acc);
        proj[idx] = acc;
    }
    if (idx < NPROJ * HID) {
        int j = idx / HID, k = idx - j * HID;
        w_t[k * NPROJ + j] = w_hh[idx];
    }
}

// 384 threads = 6 waves, one CU.
// Row map: waves 0-3 -> row R=tid, k in [0,100).  wave 4 -> R=256+lane (lane<44),
// k in [0,52).  wave 5 -> same rows, k in [52,100).  u[] holds full values for
// R<256 and two partials (at R and R+44) for R>=256; phase B sums the partials.
// h is per-wave private in LDS (float4 broadcast reads); ONE barrier per step.
__global__ __launch_bounds__(384) __attribute__((amdgpu_waves_per_eu(2, 2)))
void gru_seq_kernel(const int*   __restrict__ x,
                    const float* __restrict__ b_hh,
                    const float* __restrict__ proj,
                    const float* __restrict__ w_t,
                    float* __restrict__ out)
{
    __shared__ float h_priv[6][104];
    __shared__ float u[2][352];

    const int tid  = threadIdx.x;
    const int wave = tid >> 6;
    const int lane = tid & 63;

    const int  l1   = (lane < 36) ? lane : 35;   // second h index (clamped)
    const bool has1 = (lane < 36);

    int  R;
    bool active;
    if (wave < 4) { R = tid; active = true; }
    else          { R = 256 + ((lane < 44) ? lane : 43); active = (lane < 44); }
    const int uidx = (wave == 5) ? (R + 44) : R;   // partial1 slot at R+44

    // Persistent weights in VGPRs (waves_per_eu(2,2) -> 256-VGPR budget, no spill)
    float w[100];
    if (wave < 4) {
        #pragma unroll
        for (int k = 0; k < 100; ++k) w[k] = w_t[k * NPROJ + R];
    } else if (wave == 4) {
        #pragma unroll
        for (int k = 0; k < 52; ++k)  w[k] = w_t[k * NPROJ + R];
    } else {
        #pragma unroll
        for (int k = 52; k < 100; ++k) w[k] = w_t[k * NPROJ + R];
    }

    // Per-step phase-A init: proj lookup for R<200 rows, b_hn for n-rows, 0 for
    // the k-high partial (bias must not be double-counted).
    const bool  needs_proj = (wave < 4) && (R < 200);
    const float init_const = (wave == 5) ? 0.0f
                           : ((wave == 4 || R >= 200) ? b_hh[R] : 0.0f);

    h_priv[wave][lane] = 0.0f;
    if (lane < 40) h_priv[wave][64 + lane] = 0.0f;
    float hold0 = 0.0f, hold1 = 0.0f;

    // Software-pipelined token/proj lookups (1 step of slack, L2-resident).
    int tok = x[0];
    float xpA = needs_proj ? proj[tok * NPROJ + R] : init_const;
    float xn0 = proj[tok * NPROJ + 200 + lane];
    float xn1 = proj[tok * NPROJ + 264 + l1];
    int tok_next = x[1];

    __syncthreads();

    for (int t = 0; t < SEQN; ++t) {
        const int buf = t & 1;

        // Prefetch step t+1 inputs.
        int   tok_nn = x[(t + 2 < SEQN) ? (t + 2) : (SEQN - 1)];
        float xpA_n  = needs_proj ? proj[tok_next * NPROJ + R] : init_const;
        float xn0_n  = proj[tok_next * NPROJ + 200 + lane];
        float xn1_n  = proj[tok_next * NPROJ + 264 + l1];

        // ---- Phase A: u[R] (+=) W_hh[R]·h over this thread's k-range ----
        const float* hp = h_priv[wave];
        float a0 = xpA, a1 = 0.0f, a2 = 0.0f, a3 = 0.0f;
        if (wave < 4) {
            #pragma unroll
            for (int k = 0; k < 100; k += 4) {
                float4 hv = *(const float4*)(hp + k);
                a0 = fmaf(w[k],     hv.x, a0);
                a1 = fmaf(w[k + 1], hv.y, a1);
                a2 = fmaf(w[k + 2], hv.z, a2);
                a3 = fmaf(w[k + 3], hv.w, a3);
            }
        } else if (wave == 4) {
            #pragma unroll
            for (int k = 0; k < 52; k += 4) {
                float4 hv = *(const float4*)(hp + k);
                a0 = fmaf(w[k],     hv.x, a0);
                a1 = fmaf(w[k + 1], hv.y, a1);
                a2 = fmaf(w[k + 2], hv.z, a2);
                a3 = fmaf(w[k + 3], hv.w, a3);
            }
        } else {
            #pragma unroll
            for (int k = 52; k < 100; k += 4) {
                float4 hv = *(const float4*)(hp + k);
                a0 = fmaf(w[k],     hv.x, a0);
                a1 = fmaf(w[k + 1], hv.y, a1);
                a2 = fmaf(w[k + 2], hv.z, a2);
                a3 = fmaf(w[k + 3], hv.w, a3);
            }
        }
        if (active) u[buf][uidx] = (a0 + a1) + (a2 + a3);
        __syncthreads();   // the ONLY barrier per step

        // ---- Phase B (redundant per wave): gates + h update ----
        const float* ub = u[buf];
        float ur0 = ub[lane];
        float uz0 = ub[100 + lane];
        float un0 = ub[200 + lane];
        if (lane >= 56) un0 += ub[244 + lane];     // rows >=256: add partial1
        float ur1 = ub[64 + l1];
        float uz1 = ub[164 + l1];
        float un1 = ub[264 + l1] + ub[308 + l1];   // always split rows

        float r0  = fast_sig(ur0);
        float z0  = fast_sig(uz0);
        float n0  = fast_tanh(xn0 + r0 * un0);
        float hn0 = n0 + z0 * (hold0 - n0);

        float r1  = fast_sig(ur1);
        float z1  = fast_sig(uz1);
        float n1  = fast_tanh(xn1 + r1 * un1);
        float hn1 = n1 + z1 * (hold1 - n1);

        h_priv[wave][lane] = hn0;
        hold0 = hn0;
        if (has1) { h_priv[wave][64 + lane] = hn1; hold1 = hn1; }

        tok = tok_next;  tok_next = tok_nn;
        xpA = xpA_n;  xn0 = xn0_n;  xn1 = xn1_n;
    }

    if (wave == 0) {
        out[lane] = hold0;                 // h[0..63]
        if (has1) out[64 + lane] = hold1;  // h[64..99]
    }
}

extern "C" void kernel_launch(void* const* d_in, const int* in_sizes, int n_in,
                              void* d_out, int out_size, void* d_ws, size_t ws_size,
                              hipStream_t stream)
{
    const int*   x    = (const int*)  d_in[0];
    const float* emb  = (const float*)d_in[1];
    const float* w_ih = (const float*)d_in[2];
    const float* w_hh = (const float*)d_in[3];
    const float* b_ih = (const float*)d_in[4];
    const float* b_hh = (const float*)d_in[5];
    float* out = (float*)d_out;

    float* proj = (float*)d_ws;              // 60*300 f32 = 72 KB
    float* w_t  = proj + VOCAB * NPROJ;      // 100*300 f32 = 120 KB

    const int total = NPROJ * HID;           // 30000 covers both precompute jobs
    precompute_kernel<<<(total + 255) / 256, 256, 0, stream>>>(
        emb, w_ih, b_ih, b_hh, w_hh, proj, w_t);
    gru_seq_kernel<<<1, 384, 0, stream>>>(x, b_hh, proj, w_t, out);
}

// Round 3
// 188580.408 us; speedup vs baseline: 1.1464x; 1.1464x over previous
//
#include <hip/hip_runtime.h>

#define VOCAB 60
#define EMB   100
#define HID   100
#define SEQN  262144
#define NPROJ 300   // 3*HID

typedef float f32x2  __attribute__((ext_vector_type(2)));
typedef float f32x4  __attribute__((ext_vector_type(4)));
typedef float f32x32 __attribute__((ext_vector_type(32)));

__device__ __forceinline__ float fast_sig(float x) {
    return __builtin_amdgcn_rcpf(1.0f + __builtin_amdgcn_exp2f(-1.442695041f * x));
}
__device__ __forceinline__ float fast_tanh(float x) {
    return 2.0f * __builtin_amdgcn_rcpf(1.0f + __builtin_amdgcn_exp2f(-2.885390082f * x)) - 1.0f;
}

#if __has_builtin(__builtin_elementwise_fma)
#define PKFMA(A, B, C) __builtin_elementwise_fma((A), (B), (C))
#else
__device__ __forceinline__ f32x2 pkfma_(f32x2 a, f32x2 b, f32x2 c) {
    f32x2 r; r.x = fmaf(a.x, b.x, c.x); r.y = fmaf(a.y, b.y, c.y); return r;
}
#define PKFMA pkfma_
#endif

// Pair extract with PARSE-TIME-CONSTANT indices only (keeps vectors in SSA regs).
#define SH2(V, I) __builtin_shufflevector((V), (V), (I), (I) + 1)
#define WPV(K) ((K) < 32 ? SH2(wv0, (K) & 31) \
              : (K) < 64 ? SH2(wv1, (K) & 31) \
              : (K) < 96 ? SH2(wv2, (K) & 31) \
                         : SH2(wv3, (K) & 3))
// One float4 of h, two packed FMAs into two rotating accumulators.
#define HSTEP(K, A0, A1) {                                   \
    f32x4 hv_ = *(const f32x4*)(hp + (K));                   \
    A0 = PKFMA(WPV(K),       SH2(hv_, 0), A0);               \
    A1 = PKFMA(WPV((K) + 2), SH2(hv_, 2), A1); }

// proj[v][j] = emb[v]·w_ih[j] + b_ih[j] + (j<200 ? b_hh[j] : 0)
__global__ void precompute_kernel(const float* __restrict__ emb,
                                  const float* __restrict__ w_ih,
                                  const float* __restrict__ b_ih,
                                  const float* __restrict__ b_hh,
                                  float* __restrict__ proj)
{
    int idx = blockIdx.x * blockDim.x + threadIdx.x;
    if (idx < VOCAB * NPROJ) {
        int v = idx / NPROJ, j = idx - v * NPROJ;
        float acc = b_ih[j] + (j < 2 * HID ? b_hh[j] : 0.0f);
        const float* er = emb  + v * EMB;
        const float* wr = w_ih + j * EMB;
        #pragma unroll 4
        for (int k = 0; k < EMB; ++k) acc = fmaf(er[k], wr[k], acc);
        proj[idx] = acc;
    }
}

// 384 threads = 6 waves, one CU.
// waves 0-3: row R=tid, k in [0,100).  wave 4: R=256+lane (lane<44), k in [0,52).
// wave 5: same rows, k in [52,100).  u[] holds full values for R<256 and two
// partials (R and R+44) for R>=256. h per-wave private in LDS; ONE barrier/step.
// Weights live in named ext_vector SSA registers (wv0..wv3) -> cannot go to scratch.
__global__ __launch_bounds__(384) __attribute__((amdgpu_waves_per_eu(2, 2)))
void gru_seq_kernel(const int*   __restrict__ x,
                    const float* __restrict__ b_hh,
                    const float* __restrict__ proj,
                    const float* __restrict__ w_hh,
                    float* __restrict__ out)
{
    __shared__ __align__(16) float h_priv[6][104];
    __shared__ float u[2][352];

    const int tid  = threadIdx.x;
    const int wave = tid >> 6;
    const int lane = tid & 63;

    const int  l1   = (lane < 36) ? lane : 35;   // second h index (clamped)
    const bool has1 = (lane < 36);

    int  R;
    bool active;
    if (wave < 4) { R = tid; active = true; }
    else          { R = 256 + ((lane < 44) ? lane : 43); active = (lane < 44); }
    const int uidx = (wave == 5) ? (R + 44) : R;   // partial1 slot at R+44

    // Full weight row in named vector registers (loaded once, straight from w_hh).
    const float* wrow = w_hh + R * HID;
    f32x32 wv0, wv1, wv2; f32x4 wv3;
    __builtin_memcpy(&wv0, wrow,      sizeof(wv0));
    __builtin_memcpy(&wv1, wrow + 32, sizeof(wv1));
    __builtin_memcpy(&wv2, wrow + 64, sizeof(wv2));
    __builtin_memcpy(&wv3, wrow + 96, sizeof(wv3));

    const bool  needs_proj = (wave < 4) && (R < 200);
    const float init_const = (wave == 5) ? 0.0f
                           : ((wave == 4 || R >= 200) ? b_hh[R] : 0.0f);

    h_priv[wave][lane] = 0.0f;
    if (lane < 40) h_priv[wave][64 + lane] = 0.0f;
    float hold0 = 0.0f, hold1 = 0.0f;

    // Software-pipelined token/proj lookups (1 step of slack, L2-resident).
    int tok = x[0];
    float xpA = needs_proj ? proj[tok * NPROJ + R] : init_const;
    float xn0 = proj[tok * NPROJ + 200 + lane];
    float xn1 = proj[tok * NPROJ + 264 + l1];
    int tok_next = x[1];

    __syncthreads();

    for (int t = 0; t < SEQN; ++t) {
        const int buf = t & 1;

        // Prefetch step t+1 inputs.
        int   tok_nn = x[(t + 2 < SEQN) ? (t + 2) : (SEQN - 1)];
        float xpA_n  = needs_proj ? proj[tok_next * NPROJ + R] : init_const;
        float xn0_n  = proj[tok_next * NPROJ + 200 + lane];
        float xn1_n  = proj[tok_next * NPROJ + 264 + l1];

        // ---- Phase A: u[R] = init + W_hh[R]·h over this thread's k-range ----
        const float* hp = h_priv[wave];
        f32x2 acc0 = {xpA, 0.0f}, acc1 = {0.0f, 0.0f},
              acc2 = {0.0f, 0.0f}, acc3 = {0.0f, 0.0f};
        if (wave < 4) {
            HSTEP(0,  acc0, acc1) HSTEP(4,  acc2, acc3)
            HSTEP(8,  acc0, acc1) HSTEP(12, acc2, acc3)
            HSTEP(16, acc0, acc1) HSTEP(20, acc2, acc3)
            HSTEP(24, acc0, acc1) HSTEP(28, acc2, acc3)
            HSTEP(32, acc0, acc1) HSTEP(36, acc2, acc3)
            HSTEP(40, acc0, acc1) HSTEP(44, acc2, acc3)
            HSTEP(48, acc0, acc1) HSTEP(52, acc2, acc3)
            HSTEP(56, acc0, acc1) HSTEP(60, acc2, acc3)
            HSTEP(64, acc0, acc1) HSTEP(68, acc2, acc3)
            HSTEP(72, acc0, acc1) HSTEP(76, acc2, acc3)
            HSTEP(80, acc0, acc1) HSTEP(84, acc2, acc3)
            HSTEP(88, acc0, acc1) HSTEP(92, acc2, acc3)
            HSTEP(96, acc0, acc1)
        } else if (wave == 4) {            // k in [0,52)
            HSTEP(0,  acc0, acc1) HSTEP(4,  acc2, acc3)
            HSTEP(8,  acc0, acc1) HSTEP(12, acc2, acc3)
            HSTEP(16, acc0, acc1) HSTEP(20, acc2, acc3)
            HSTEP(24, acc0, acc1) HSTEP(28, acc2, acc3)
            HSTEP(32, acc0, acc1) HSTEP(36, acc2, acc3)
            HSTEP(40, acc0, acc1) HSTEP(44, acc2, acc3)
            HSTEP(48, acc0, acc1)
        } else {                           // k in [52,100)
            HSTEP(52, acc0, acc1) HSTEP(56, acc2, acc3)
            HSTEP(60, acc0, acc1) HSTEP(64, acc2, acc3)
            HSTEP(68, acc0, acc1) HSTEP(72, acc2, acc3)
            HSTEP(76, acc0, acc1) HSTEP(80, acc2, acc3)
            HSTEP(84, acc0, acc1) HSTEP(88, acc2, acc3)
            HSTEP(92, acc0, acc1) HSTEP(96, acc2, acc3)
        }
        f32x2 s2 = (acc0 + acc1) + (acc2 + acc3);
        if (active) u[buf][uidx] = s2.x + s2.y;
        __syncthreads();   // the ONLY barrier per step

        // ---- Phase B (redundant per wave): gates + h update ----
        const float* ub = u[buf];
        float ur0 = ub[lane];
        float uz0 = ub[100 + lane];
        float un0 = ub[200 + lane];
        if (lane >= 56) un0 += ub[244 + lane];     // rows >=256: add partial1
        float ur1 = ub[64 + l1];
        float uz1 = ub[164 + l1];
        float un1 = ub[264 + l1] + ub[308 + l1];   // always split rows

        float r0  = fast_sig(ur0);
        float z0  = fast_sig(uz0);
        float n0  = fast_tanh(xn0 + r0 * un0);
        float hn0 = n0 + z0 * (hold0 - n0);

        float r1  = fast_sig(ur1);
        float z1  = fast_sig(uz1);
        float n1  = fast_tanh(xn1 + r1 * un1);
        float hn1 = n1 + z1 * (hold1 - n1);

        h_priv[wave][lane] = hn0;
        hold0 = hn0;
        if (has1) { h_priv[wave][64 + lane] = hn1; hold1 = hn1; }

        tok = tok_next;  tok_next = tok_nn;
        xpA = xpA_n;  xn0 = xn0_n;  xn1 = xn1_n;
    }

    if (wave == 0) {
        out[lane] = hold0;                 // h[0..63]
        if (has1) out[64 + lane] = hold1;  // h[64..99]
    }
}

extern "C" void kernel_launch(void* const* d_in, const int* in_sizes, int n_in,
                              void* d_out, int out_size, void* d_ws, size_t ws_size,
                              hipStream_t stream)
{
    const int*   x    = (const int*)  d_in[0];
    const float* emb  = (const float*)d_in[1];
    const float* w_ih = (const float*)d_in[2];
    const float* w_hh = (const float*)d_in[3];
    const float* b_ih = (const float*)d_in[4];
    const float* b_hh = (const float*)d_in[5];
    float* out = (float*)d_out;

    float* proj = (float*)d_ws;              // 60*300 f32 = 72 KB scratch

    const int total = VOCAB * NPROJ;         // 18000
    precompute_kernel<<<(total + 255) / 256, 256, 0, stream>>>(
        emb, w_ih, b_ih, b_hh, proj);
    gru_seq_kernel<<<1, 384, 0, stream>>>(x, b_hh, proj, w_hh, out);
}